// Round 1
// baseline (101.522 us; speedup 1.0000x reference)
//
#include <hip/hip_runtime.h>

#define NROWS 8192
#define KD    128
#define K1C   20.6099291260f   /* log2(e)/0.07 */

typedef __bf16 bf16x8 __attribute__((ext_vector_type(8)));
typedef float  f32x4  __attribute__((ext_vector_type(4)));

typedef __attribute__((address_space(1))) void* gas_ptr;
typedef __attribute__((address_space(3))) void* las_ptr;

__device__ __forceinline__ unsigned short f2bf(float x) {
  unsigned int u = __builtin_bit_cast(unsigned int, x);
  unsigned int r = (u + 0x7FFFu + ((u >> 16) & 1u)) >> 16;  // RNE
  return (unsigned short)r;
}

// Convert both fp32 inputs to bf16 in ws, zero the 4 sum arrays.
__global__ __launch_bounds__(256) void prep_kernel(const float4* __restrict__ F4,
                                                   const float4* __restrict__ M4,
                                                   ushort4* __restrict__ Fb4,
                                                   ushort4* __restrict__ Mb4,
                                                   float* __restrict__ sums) {
  int i = blockIdx.x * 256 + threadIdx.x;   // 0 .. 262143 (each handles 4 elems)
  float4 f = F4[i];
  float4 m = M4[i];
  ushort4 fo, mo;
  fo.x = f2bf(f.x); fo.y = f2bf(f.y); fo.z = f2bf(f.z); fo.w = f2bf(f.w);
  mo.x = f2bf(m.x); mo.y = f2bf(m.y); mo.z = f2bf(m.z); mo.w = f2bf(m.w);
  Fb4[i] = fo;
  Mb4[i] = mo;
  if (i < 4 * NROWS) sums[i] = 0.0f;
}

// z=0: FM (rowsum->Spos_f, colsum->Spos_m). z=1: FF (rowsum->Sneg_f, diag masked).
// z=2: MM (rowsum->Sneg_m, diag masked).
// Tile: 128 rows (by) x 1024 cols (bx) per WG, 8 inner col-tiles of 128.
// A tile in registers; B double-buffered in LDS via global_load_lds (swizzled source).
__global__ __launch_bounds__(256, 2) void gemm_kernel(const unsigned short* __restrict__ Fb,
                                                      const unsigned short* __restrict__ Mb,
                                                      float* __restrict__ sums) {
  __shared__ __align__(16) unsigned short lds[2][128 * 128];  // 2 x 32KB

  const int bx = blockIdx.x;   // 0..7   col split
  const int by = blockIdx.y;   // 0..63  row block
  const int z  = blockIdx.z;   // 0..2   which GEMM

  const unsigned short* A;
  const unsigned short* B;
  float* rowsum;
  float* colsum = nullptr;
  if (z == 0)      { A = Fb; B = Mb; rowsum = sums;             colsum = sums + NROWS; }
  else if (z == 1) { A = Fb; B = Fb; rowsum = sums + 2 * NROWS; }
  else             { A = Mb; B = Mb; rowsum = sums + 3 * NROWS; }

  const int tid  = threadIdx.x;
  const int lane = tid & 63;
  const int wave = tid >> 6;        // 0..3
  const int wr = wave >> 1, wc = wave & 1;
  const int l15 = lane & 15, l4 = lane >> 4;

  // Stage 32KB (128 rows x 256B) global->LDS. LDS dest linear (gld_lds requirement);
  // global source pre-permuted with the same XOR the reads use (rule 21).
  auto stage = [&](unsigned short* dst, const unsigned short* src) {
    #pragma unroll
    for (int i = 0; i < 8; ++i) {
      const int c   = wave * 8 + i;          // 1KB chunk
      const int lin = c * 1024 + lane * 16;  // linear byte offset in tile
      const int row = lin >> 8;
      const int bc  = lin & 255;
      const int sbc = bc ^ ((row & 7) << 4);
      const char* s = (const char*)src + row * 256 + sbc;
      char* d = (char*)dst + c * 1024;       // wave-uniform base (c uniform per wave)
      __builtin_amdgcn_global_load_lds((gas_ptr)s, (las_ptr)d, 16, 0, 0);
    }
  };

  // ---- A tile -> registers (16 swizzled ds_read_b128 per lane)
  stage(lds[0], A + (size_t)by * 128 * KD);
  __syncthreads();

  bf16x8 afrag[4][4];
  #pragma unroll
  for (int m = 0; m < 4; ++m) {
    #pragma unroll
    for (int k = 0; k < 4; ++k) {
      const int row = wr * 64 + m * 16 + l15;
      const int bc  = k * 64 + l4 * 16;
      afrag[m][k] = *(const bf16x8*)((const char*)lds[0] + row * 256 + (bc ^ ((row & 7) << 4)));
    }
  }
  __syncthreads();   // drain reads before lds[0] is re-staged with B0

  float rowacc[16];
  #pragma unroll
  for (int i = 0; i < 16; ++i) rowacc[i] = 0.f;

  const unsigned short* Bbase = B + (size_t)bx * 1024 * KD;
  stage(lds[0], Bbase);
  __syncthreads();

  for (int t = 0; t < 8; ++t) {
    if (t < 7) stage(lds[(t + 1) & 1], Bbase + (size_t)(t + 1) * 128 * KD);  // prefetch

    f32x4 acc[4][4] = {};
    const char* bufB = (const char*)lds[t & 1];
    #pragma unroll
    for (int k = 0; k < 4; ++k) {
      bf16x8 bfrag[4];
      #pragma unroll
      for (int n = 0; n < 4; ++n) {
        const int row = wc * 64 + n * 16 + l15;
        const int bc  = k * 64 + l4 * 16;
        bfrag[n] = *(const bf16x8*)(bufB + row * 256 + (bc ^ ((row & 7) << 4)));
      }
      #pragma unroll
      for (int m = 0; m < 4; ++m)
        #pragma unroll
        for (int n = 0; n < 4; ++n)
          acc[m][n] = __builtin_amdgcn_mfma_f32_16x16x32_bf16(afrag[m][k], bfrag[n], acc[m][n], 0, 0, 0);
    }

    // Epilogue: v = exp((sim-1)/T); accumulate row sums (regs) and col sums (z==0).
    const bool doMask = (z > 0) && (bx * 8 + t == by);  // this col-tile holds the diagonal
    float colacc[4] = {0.f, 0.f, 0.f, 0.f};
    #pragma unroll
    for (int m = 0; m < 4; ++m) {
      #pragma unroll
      for (int n = 0; n < 4; ++n) {
        #pragma unroll
        for (int j = 0; j < 4; ++j) {
          float v = __builtin_amdgcn_exp2f((acc[m][n][j] - 1.0f) * K1C);
          if (doMask) {
            const int lr = wr * 64 + m * 16 + l4 * 4 + j;   // C/D: row=(lane>>4)*4+reg
            const int lc = wc * 64 + n * 16 + l15;          //      col=lane&15
            if (lr == lc) v = 0.f;                           // mask self-similarity
          }
          rowacc[m * 4 + j] += v;
          if (z == 0) colacc[n] += v;
        }
      }
    }
    if (z == 0) {
      #pragma unroll
      for (int n = 0; n < 4; ++n) {
        float v = colacc[n];
        v += __shfl_xor(v, 16);
        v += __shfl_xor(v, 32);
        if (lane < 16)
          unsafeAtomicAdd(colsum + bx * 1024 + t * 128 + wc * 64 + n * 16 + lane, v);
      }
    }
    __syncthreads();  // drains prefetch vmcnt + protects buffer swap
  }

  // Flush row sums once per WG: butterfly over lane&15, then 4 active lanes atomic.
  #pragma unroll
  for (int i = 0; i < 16; ++i) {
    float v = rowacc[i];
    v += __shfl_xor(v, 1);
    v += __shfl_xor(v, 2);
    v += __shfl_xor(v, 4);
    v += __shfl_xor(v, 8);
    rowacc[i] = v;
  }
  if (l15 == 0) {
    const int rbase = by * 128 + wr * 64 + l4 * 4;
    #pragma unroll
    for (int i = 0; i < 16; ++i)
      unsafeAtomicAdd(rowsum + rbase + (i >> 2) * 16 + (i & 3), rowacc[i]);
  }
}

// loss = 1.5*mean(log1p(Sneg_f/Spos_f)) + 0.5*mean(log1p(Sneg_m/Spos_m))
__global__ __launch_bounds__(256) void loss_kernel(const float* __restrict__ sums,
                                                   float* __restrict__ out) {
  const float* Spf = sums;
  const float* Spm = sums + NROWS;
  const float* Snf = sums + 2 * NROWS;
  const float* Snm = sums + 3 * NROWS;
  float accf = 0.f, accm = 0.f;
  for (int i = threadIdx.x; i < NROWS; i += 256) {
    accf += log1pf(Snf[i] / Spf[i]);
    accm += log1pf(Snm[i] / Spm[i]);
  }
  float v = 1.5f * accf + 0.5f * accm;
  #pragma unroll
  for (int s = 1; s < 64; s <<= 1) v += __shfl_xor(v, s);
  __shared__ float red[4];
  if ((threadIdx.x & 63) == 0) red[threadIdx.x >> 6] = v;
  __syncthreads();
  if (threadIdx.x == 0) out[0] = (red[0] + red[1] + red[2] + red[3]) * (1.0f / NROWS);
}

extern "C" void kernel_launch(void* const* d_in, const int* in_sizes, int n_in,
                              void* d_out, int out_size, void* d_ws, size_t ws_size,
                              hipStream_t stream) {
  (void)in_sizes; (void)n_in; (void)out_size; (void)ws_size;
  const float* F = (const float*)d_in[0];
  const float* M = (const float*)d_in[1];
  float* out = (float*)d_out;

  // ws layout: [4*8192 f32 sums][8192*128 bf16 F][8192*128 bf16 M]  (~4.3 MB)
  float* sums = (float*)d_ws;
  unsigned short* Fb = (unsigned short*)((char*)d_ws + 4 * NROWS * sizeof(float));
  unsigned short* Mb = Fb + (size_t)NROWS * KD;

  prep_kernel<<<dim3(NROWS * KD / 4 / 256), dim3(256), 0, stream>>>(
      (const float4*)F, (const float4*)M, (ushort4*)Fb, (ushort4*)Mb, sums);
  gemm_kernel<<<dim3(8, 64, 3), dim3(256), 0, stream>>>(Fb, Mb, sums);
  loss_kernel<<<dim3(1), dim3(256), 0, stream>>>(sums, out);
}

// Round 2
// 100.494 us; speedup vs baseline: 1.0102x; 1.0102x over previous
//
#include <hip/hip_runtime.h>

#define NROWS 8192
#define KD    128
#define K1C   20.6099291260f   /* log2(e)/0.07 */

typedef __bf16 bf16x8 __attribute__((ext_vector_type(8)));
typedef float  f32x16 __attribute__((ext_vector_type(16)));

typedef __attribute__((address_space(1))) void* gas_ptr;
typedef __attribute__((address_space(3))) void* las_ptr;

__device__ __forceinline__ unsigned short f2bf(float x) {
  unsigned int u = __builtin_bit_cast(unsigned int, x);
  unsigned int r = (u + 0x7FFFu + ((u >> 16) & 1u)) >> 16;  // RNE
  return (unsigned short)r;
}

// Convert both fp32 inputs to bf16 in ws, zero the 4 sum arrays.
__global__ __launch_bounds__(256) void prep_kernel(const float4* __restrict__ F4,
                                                   const float4* __restrict__ M4,
                                                   ushort4* __restrict__ Fb4,
                                                   ushort4* __restrict__ Mb4,
                                                   float* __restrict__ sums) {
  int i = blockIdx.x * 256 + threadIdx.x;
  float4 f = F4[i];
  float4 m = M4[i];
  ushort4 fo, mo;
  fo.x = f2bf(f.x); fo.y = f2bf(f.y); fo.z = f2bf(f.z); fo.w = f2bf(f.w);
  mo.x = f2bf(m.x); mo.y = f2bf(m.y); mo.z = f2bf(m.z); mo.w = f2bf(m.w);
  Fb4[i] = fo;
  Mb4[i] = mo;
  if (i < 4 * NROWS) sums[i] = 0.0f;
}

// z=0: FM (rowsum->Spos_f, colsum->Spos_m). z=1: FF (rowsum->Sneg_f, diag masked).
// z=2: MM (rowsum->Sneg_m, diag masked).
// WG: 512 threads (8 waves, 4 row x 2 col), strip 128 rows x 1024 cols, 8 B-chunks.
// A in registers (32 rows/wave x K128 = 32 VGPR); B double-buffered 2x32KB LDS.
// 32x32x16 MFMA; XOR-swizzled LDS (linear dest via global_load_lds, pre-swizzled src).
__global__ __launch_bounds__(512, 4) void gemm_kernel(const unsigned short* __restrict__ Fb,
                                                      const unsigned short* __restrict__ Mb,
                                                      float* __restrict__ sums) {
  __shared__ __align__(16) unsigned short lds[2][128 * 128];  // 2 x 32KB

  const int bx = blockIdx.x;   // 0..7   col split
  const int by = blockIdx.y;   // 0..63  row block
  const int z  = blockIdx.z;   // 0..2

  const unsigned short* A;
  const unsigned short* B;
  float* rowsum;
  float* colsum = nullptr;
  if (z == 0)      { A = Fb; B = Mb; rowsum = sums;             colsum = sums + NROWS; }
  else if (z == 1) { A = Fb; B = Fb; rowsum = sums + 2 * NROWS; }
  else             { A = Mb; B = Mb; rowsum = sums + 3 * NROWS; }

  const int tid  = threadIdx.x;
  const int lane = tid & 63;
  const int wave = tid >> 6;          // 0..7
  const int wr = wave >> 1;           // 0..3 row band (32 rows each)
  const int wc = wave & 1;            // 0..1 col band (64 cols each)
  const int l31 = lane & 31, lh = lane >> 5;

  // Staging: thread tid owns linear bytes [tid*16, tid*16+16) (+i*8192) of a 32KB tile.
  // LDS dest linear; global source pre-XORed with the read-side swizzle (rule 21).
  const int srow = tid >> 4;
  const int soff = srow * 256 + ((((tid & 15) * 16)) ^ ((srow & 7) << 4));

#define STAGE(dstbuf, src) do {                                                          \
    const char* s_ = (const char*)(src) + soff;                                          \
    char* d_ = (char*)(dstbuf) + tid * 16;                                               \
    __builtin_amdgcn_global_load_lds((gas_ptr)(s_),         (las_ptr)(d_),         16, 0, 0); \
    __builtin_amdgcn_global_load_lds((gas_ptr)(s_ + 8192),  (las_ptr)(d_ + 8192),  16, 0, 0); \
    __builtin_amdgcn_global_load_lds((gas_ptr)(s_ + 16384), (las_ptr)(d_ + 16384), 16, 0, 0); \
    __builtin_amdgcn_global_load_lds((gas_ptr)(s_ + 24576), (las_ptr)(d_ + 24576), 16, 0, 0); \
  } while (0)

  const unsigned short* Abase = A + (size_t)by * 128 * KD;
  const unsigned short* Bbase = B + (size_t)bx * 1024 * KD;

  STAGE(lds[0], Abase);   // A strip 128x128
  STAGE(lds[1], Bbase);   // B chunk 0
  __syncthreads();

  // A fragments: wave owns rows [wr*32, wr*32+32). 32x32x16 A-operand:
  // lane holds row (l&31), k = (l>>5)*8 + e  => 16B contiguous at byte k-col.
  bf16x8 afrag[8];
  {
    const int arow = wr * 32 + l31;
    const char* ab = (const char*)lds[0] + arow * 256;
    const int sw = (arow & 7) << 4;
    #pragma unroll
    for (int ks = 0; ks < 8; ++ks)
      afrag[ks] = *(const bf16x8*)(ab + ((ks * 32 + lh * 16) ^ sw));
  }

  float rowacc[16];
  #pragma unroll
  for (int i = 0; i < 16; ++i) rowacc[i] = 0.f;

  __syncthreads();   // afrag reads drained before lds[0] is re-staged (t=0 below)

  const int brow = wc * 64 + l31;            // n=0 B row (output col); n=1 adds 32
  const int bsw  = (brow & 7) << 4;          // (brow+32)&7 == brow&7

  for (int t = 0; t < 8; ++t) {
    if (t < 7) STAGE(lds[t & 1], Bbase + (size_t)(t + 1) * 128 * KD);  // prefetch

    const char* bb = (const char*)lds[(t + 1) & 1];
    const char* bb0 = bb + brow * 256;
    const char* bb1 = bb0 + 32 * 256;

    f32x16 acc0 = {}, acc1 = {};
    #pragma unroll
    for (int ks = 0; ks < 8; ++ks) {
      const int c = (ks * 32 + lh * 16);
      bf16x8 b0 = *(const bf16x8*)(bb0 + (c ^ bsw));
      bf16x8 b1 = *(const bf16x8*)(bb1 + (c ^ bsw));
      acc0 = __builtin_amdgcn_mfma_f32_32x32x16_bf16(afrag[ks], b0, acc0, 0, 0, 0);
      acc1 = __builtin_amdgcn_mfma_f32_32x32x16_bf16(afrag[ks], b1, acc1, 0, 0, 0);
    }

    // Epilogue: v = exp2(sim*K1C - K1C); rowacc in regs; colsum (z==0) via shfl+atomic.
    // C/D 32x32: col = lane&31, row = (r&3) + 8*(r>>2) + 4*(lane>>5)
    const bool diag = (z > 0) && (bx * 8 + t == by);
    if (z == 0) {
      float col0 = 0.f, col1 = 0.f;
      #pragma unroll
      for (int r = 0; r < 16; ++r) {
        float v0 = __builtin_amdgcn_exp2f(acc0[r] * K1C - K1C);
        float v1 = __builtin_amdgcn_exp2f(acc1[r] * K1C - K1C);
        rowacc[r] += v0 + v1;
        col0 += v0; col1 += v1;
      }
      col0 += __shfl_xor(col0, 32);
      col1 += __shfl_xor(col1, 32);
      if (lh == 0) {
        float* cp = colsum + bx * 1024 + t * 128 + wc * 64 + l31;
        unsafeAtomicAdd(cp, col0);
        unsafeAtomicAdd(cp + 32, col1);
      }
    } else {
      #pragma unroll
      for (int r = 0; r < 16; ++r) {
        float v0 = __builtin_amdgcn_exp2f(acc0[r] * K1C - K1C);
        float v1 = __builtin_amdgcn_exp2f(acc1[r] * K1C - K1C);
        if (diag) {
          const int lr = wr * 32 + (r & 3) + 8 * (r >> 2) + 4 * lh;
          const int lc = wc * 64 + l31;
          if (lr == lc)      v0 = 0.f;
          if (lr == lc + 32) v1 = 0.f;
        }
        rowacc[r] += v0 + v1;
      }
    }
    __syncthreads();  // drains prefetch vmcnt + protects buffer swap
  }

  // Flush row sums: butterfly over the 32-lane col group, then 2 lanes do atomics.
  #pragma unroll
  for (int i = 0; i < 16; ++i) {
    float v = rowacc[i];
    v += __shfl_xor(v, 1);
    v += __shfl_xor(v, 2);
    v += __shfl_xor(v, 4);
    v += __shfl_xor(v, 8);
    v += __shfl_xor(v, 16);
    rowacc[i] = v;
  }
  if (l31 == 0) {
    const int rbase = by * 128 + wr * 32 + 4 * lh;
    #pragma unroll
    for (int i = 0; i < 16; ++i)
      unsafeAtomicAdd(rowsum + rbase + (i & 3) + 8 * (i >> 2), rowacc[i]);
  }
#undef STAGE
}

// loss = 1.5*mean(log1p(Sneg_f/Spos_f)) + 0.5*mean(log1p(Sneg_m/Spos_m))
__global__ __launch_bounds__(1024) void loss_kernel(const float* __restrict__ sums,
                                                    float* __restrict__ out) {
  const float* Spf = sums;
  const float* Spm = sums + NROWS;
  const float* Snf = sums + 2 * NROWS;
  const float* Snm = sums + 3 * NROWS;
  float accf = 0.f, accm = 0.f;
  for (int i = threadIdx.x; i < NROWS; i += 1024) {
    accf += log1pf(Snf[i] / Spf[i]);
    accm += log1pf(Snm[i] / Spm[i]);
  }
  float v = 1.5f * accf + 0.5f * accm;
  #pragma unroll
  for (int s = 1; s < 64; s <<= 1) v += __shfl_xor(v, s);
  __shared__ float red[16];
  if ((threadIdx.x & 63) == 0) red[threadIdx.x >> 6] = v;
  __syncthreads();
  if (threadIdx.x == 0) {
    float s = 0.f;
    #pragma unroll
    for (int i = 0; i < 16; ++i) s += red[i];
    out[0] = s * (1.0f / NROWS);
  }
}

extern "C" void kernel_launch(void* const* d_in, const int* in_sizes, int n_in,
                              void* d_out, int out_size, void* d_ws, size_t ws_size,
                              hipStream_t stream) {
  (void)in_sizes; (void)n_in; (void)out_size; (void)ws_size;
  const float* F = (const float*)d_in[0];
  const float* M = (const float*)d_in[1];
  float* out = (float*)d_out;

  float* sums = (float*)d_ws;
  unsigned short* Fb = (unsigned short*)((char*)d_ws + 4 * NROWS * sizeof(float));
  unsigned short* Mb = Fb + (size_t)NROWS * KD;

  prep_kernel<<<dim3(NROWS * KD / 4 / 256), dim3(256), 0, stream>>>(
      (const float4*)F, (const float4*)M, (ushort4*)Fb, (ushort4*)Mb, sums);
  gemm_kernel<<<dim3(8, 64, 3), dim3(512), 0, stream>>>(Fb, Mb, sums);
  loss_kernel<<<dim3(1), dim3(1024), 0, stream>>>(sums, out);
}